// Round 8
// baseline (73.968 us; speedup 1.0000x reference)
//
#include <hip/hip_runtime.h>

// Polyphase resample up=3 down=2, N=2097152, L=129 taps, start=(L-1)/2=64.
// out[3j+0] = 3 * sum_i x[21+2j-i] * h[1+3i]   (i in [0,43))
// out[3j+1] = 3 * sum_i x[22+2j-i] * h[0+3i]
// out[3j+2] = 3 * sum_i x[22+2j-i] * h[2+3i]
// (formula verified across R0-R9, absmax 0.25)
//
// R10: R7 (fewer lgkm drains), R8 (2x occupancy), R9 (vector LDS) all null
// or negative => the shared stage->barrier->ds_read structure is the
// remaining suspect. This round deletes LDS entirely: each thread loads its
// chunk window directly from global as aligned float4s. The inter-thread
// reuse LDS provided (~6x overlap within a wave's ~1.1KB span) is exactly
// what L1 (32KiB/CU) serves; first touch per line misses to HBM, rest hit.
// Removes: staging loop, ds_writes, __syncthreads (8-wave serialization on
// the slowest stager), ds_reads, staging addr VALU.
// COMPILER LAW kept (R3/R6 spills vs R0/R7/R9 clean): U=16 chunks behind
// #pragma unroll 1; U=11 tail after. Only blocks 0 and last can go OOB ->
// wave-uniform edge branch with per-component guarded loads.

#define N_SIG   2097152
#define L_FILT  129
#define NTAPS   43
#define G       2            // output groups per thread (6 outputs)
#define BLK     256
#define GROUPS_PER_BLK (BLK * G)             // 512 groups -> 1536 outputs/block

__device__ __forceinline__ float ldg_guard(const float* __restrict__ x, int gx) {
    return (gx >= 0 && gx < N_SIG) ? x[gx] : 0.0f;
}

// One tap-chunk of U taps starting at runtime i0. D = 45-(i0+U-1); RP = D&3
// compile-time so unpack indices are immediates. Window = U+2G-1 words at
// global index tb + 4*tid + D + k, read as NW aligned float4s from
// gb = tb + 4*tid + (D-RP)  (tb = 1024b-24 ≡ 0 mod 4 -> 16B-aligned).
template <int U, int RP, bool EDGE>
__device__ __forceinline__ void do_chunk(const float* __restrict__ x,
                                         const float* __restrict__ h,
                                         int i0, int gbase0, float (&acc)[3 * G]) {
    const int D = 45 - (i0 + U - 1);                    // D & 3 == RP
    constexpr int NW = (RP + U + 2 * G - 1 + 3) >> 2;   // float4 count
    const int gb = gbase0 + (D - RP);
    float4 vec[NW];
#pragma unroll
    for (int m = 0; m < NW; ++m) {
        const int gx = gb + 4 * m;
        if (!EDGE) {
            vec[m] = *(const float4*)(x + gx);          // global_load_dwordx4
        } else {
            vec[m].x = ldg_guard(x, gx);
            vec[m].y = ldg_guard(x, gx + 1);
            vec[m].z = ldg_guard(x, gx + 2);
            vec[m].w = ldg_guard(x, gx + 3);
        }
    }
    const float* vf = (const float*)vec;                // const-index unpack (SROA)
#pragma unroll
    for (int u = 0; u < U; ++u) {
        // wave-uniform indices -> scalar loads, SGPR operands in the FMAs
        const float h0 = h[3 * (i0 + u) + 0];
        const float h1 = h[3 * (i0 + u) + 1];
        const float h2 = h[3 * (i0 + u) + 2];
#pragma unroll
        for (int g = 0; g < G; ++g) {
            const float xa = vf[RP + (U - 1 - u) + 2 * g];      // x[21+2j-i]
            const float xb = vf[RP + (U - 1 - u) + 2 * g + 1];  // x[22+2j-i]
            acc[3 * g + 0] += xa * h1;
            acc[3 * g + 1] += xb * h0;
            acc[3 * g + 2] += xb * h2;
        }
    }
}

__global__ __launch_bounds__(BLK, 8) void poly_kernel(
    const float* __restrict__ x, const float* __restrict__ h,
    float* __restrict__ out, int n_out)
{
    const int tid = threadIdx.x;
    const int b   = blockIdx.x;

    // Thread's window words live at global q = gbase0 + D + k,
    // gbase0 = 2*GPB*b - 24 + 4*tid (same geometry as R8/R9, LDS removed).
    const int gbase0 = 2 * GROUPS_PER_BLK * b - 24 + 4 * tid;

    float acc[3 * G];
#pragma unroll
    for (int k = 0; k < 3 * G; ++k) acc[k] = 0.0f;

    // 2 chunks of 16 taps (D = 30, 14; D&3 == 2) behind the opaque backedge
    // + tail of 11 (D = 3, D&3 == 3). Wave-uniform edge split: only blocks
    // 0 and gridDim-1 can touch gx < 0 or >= N_SIG.
    if (b != 0 && b != (int)gridDim.x - 1) {
#pragma unroll 1
        for (int i0 = 0; i0 < 32; i0 += 16)
            do_chunk<16, 2, false>(x, h, i0, gbase0, acc);
        do_chunk<11, 3, false>(x, h, 32, gbase0, acc);
    } else {
#pragma unroll 1
        for (int i0 = 0; i0 < 32; i0 += 16)
            do_chunk<16, 2, true>(x, h, i0, gbase0, acc);
        do_chunk<11, 3, true>(x, h, 32, gbase0, acc);
    }

    // 6 contiguous outputs per thread; 3x float2 (8B-aligned, coalesced).
    // Fold the up=3 gain here.
    const int ob = 3 * GROUPS_PER_BLK * b + 3 * G * tid;
#pragma unroll
    for (int k = 0; k < 3; ++k) {
        if (ob + 2 * k + 1 < n_out) {
            *(float2*)(out + ob + 2 * k) =
                make_float2(3.0f * acc[2 * k + 0], 3.0f * acc[2 * k + 1]);
        }
    }
}

extern "C" void kernel_launch(void* const* d_in, const int* in_sizes, int n_in,
                              void* d_out, int out_size, void* d_ws, size_t ws_size,
                              hipStream_t stream) {
    const float* x = (const float*)d_in[0];
    const float* h = (const float*)d_in[1];
    float* out = (float*)d_out;
    const int blocks = (out_size + 3 * GROUPS_PER_BLK - 1) / (3 * GROUPS_PER_BLK);
    poly_kernel<<<blocks, BLK, 0, stream>>>(x, h, out, out_size);
}